// Round 19
// baseline (462.355 us; speedup 1.0000x reference)
//
#include <hip/hip_runtime.h>

#define U_N 100000
#define I_N 50000
#define D_N 128
#define B_N 4
#define E_N 500000
#define NEDGE (B_N * E_N)            // 2,000,000
#define NKEYU (4 * U_N)              // keys u*4+b
#define NKEYS (NKEYU + 4 * I_N)      // 600,000
#define NMEMB (2 * NEDGE)            // 4,000,000
#define SCHUNK 2048
#define SNBLK ((NKEYS + SCHUNK - 1) / SCHUNK)   // 293
#define CB  ((NMEMB + 255) / 256)    // count/fill blocks
#define NZ4 ((NKEYS + 4) / 4)        // int4 count for offs zeroing
#define ZB  ((NZ4 + 255) / 256)      // zero-role blocks
#define TB2I ((I_N + 63) / 64)       // mfma-transform blocks, item side
#define TB2U ((U_N + 63) / 64)       // mfma-transform blocks, user side

#define SRC_MASK 0x1FFFFu            // low 17 bits: source row index
#define W_MASK   0xFFFE0000u         // high 15 bits: float top bits of weight

typedef float f32x2 __attribute__((ext_vector_type(2)));
typedef float f32x4 __attribute__((ext_vector_type(4)));
typedef short bf16x8 __attribute__((ext_vector_type(8)));
typedef unsigned int u32x4 __attribute__((ext_vector_type(4)));
typedef unsigned int u32x2 __attribute__((ext_vector_type(2)));

// round-to-nearest-even-ish bf16 pack of two floats -> uint (lo=a, hi=b)
__device__ inline unsigned int pack_bf16(float a, float b) {
    unsigned int ua = __float_as_uint(a);
    ua += 0x7FFFu + ((ua >> 16) & 1u);
    unsigned int ub = __float_as_uint(b);
    ub += 0x7FFFu + ((ub >> 16) & 1u);
    return (ua >> 16) | (ub & 0xFFFF0000u);
}

// ---------------------------------------------------------------------------
// MFMA transform: Y(bf16) = X @ W via mfma_f32_16x16x32_bf16, swapped
// operands (A = W^T frags from LDS, B = X rows). Zero-role blocks clear
// offs[]. (transform+count fusion rejected twice: r12/r14.)
// ---------------------------------------------------------------------------
__global__ __launch_bounds__(256) void transform_mfma_kernel(
    const float* __restrict__ item_emb, const float* __restrict__ user_emb,
    const float* __restrict__ u_w, const float* __restrict__ i_w,
    unsigned int* __restrict__ tA, unsigned int* __restrict__ tB,
    int4* __restrict__ offs4)
{
    __shared__ short wf[2048 * 8];   // 32 KB: A-frags, [kt(4)][ct(8)][lane(64)][8]

    const float* X; const float* W; unsigned int* Y; int N; int blk;
    if (blockIdx.x < TB2I) {
        X = item_emb; W = u_w; Y = tA; N = I_N; blk = blockIdx.x;
    } else if (blockIdx.x < TB2I + TB2U) {
        X = user_emb; W = i_w; Y = tB; N = U_N; blk = blockIdx.x - TB2I;
    } else {
        int t = (blockIdx.x - TB2I - TB2U) * 256 + threadIdx.x;
        if (t < NZ4) offs4[t] = make_int4(0, 0, 0, 0);
        return;
    }

    for (int f = threadIdx.x; f < 2048; f += 256) {
        int kt = f >> 9;
        int l  = f & 63;
        int c  = ((f >> 6) & 7) * 16 + (l & 15);
        int kb = kt * 32 + ((l >> 4) << 3);
        u32x4 q;
        q.x = pack_bf16(W[(kb + 0) * D_N + c], W[(kb + 1) * D_N + c]);
        q.y = pack_bf16(W[(kb + 2) * D_N + c], W[(kb + 3) * D_N + c]);
        q.z = pack_bf16(W[(kb + 4) * D_N + c], W[(kb + 5) * D_N + c]);
        q.w = pack_bf16(W[(kb + 6) * D_N + c], W[(kb + 7) * D_N + c]);
        *reinterpret_cast<u32x4*>(&wf[f * 8]) = q;
    }
    __syncthreads();

    int wave = threadIdx.x >> 6;
    int lane = threadIdx.x & 63;
    int rowbase = blk * 64 + wave * 16;
    if (rowbase >= N) return;

    f32x4 acc[8];
    #pragma unroll
    for (int ct = 0; ct < 8; ++ct) acc[ct] = (f32x4){0.f, 0.f, 0.f, 0.f};

    const float* xr0 = X + (size_t)(rowbase + (lane & 15)) * D_N
                         + ((lane >> 4) << 3);
    #pragma unroll
    for (int kt = 0; kt < 4; ++kt) {
        const float* xr = xr0 + kt * 32;
        float4 x0 = *reinterpret_cast<const float4*>(xr);
        float4 x1 = *reinterpret_cast<const float4*>(xr + 4);
        u32x4 bu;
        bu.x = pack_bf16(x0.x, x0.y);
        bu.y = pack_bf16(x0.z, x0.w);
        bu.z = pack_bf16(x1.x, x1.y);
        bu.w = pack_bf16(x1.z, x1.w);
        bf16x8 bfrag = __builtin_bit_cast(bf16x8, bu);
        #pragma unroll
        for (int ct = 0; ct < 8; ++ct) {
            bf16x8 afrag = *reinterpret_cast<const bf16x8*>(
                &wf[(((kt * 8 + ct) * 64) + lane) * 8]);
            acc[ct] = __builtin_amdgcn_mfma_f32_16x16x32_bf16(
                afrag, bfrag, acc[ct], 0, 0, 0);
        }
    }

    int row = rowbase + (lane & 15);
    int qd  = lane >> 4;
    unsigned int* yrow = Y + (size_t)row * (D_N / 2);
    #pragma unroll
    for (int ct = 0; ct < 8; ++ct) {
        u32x2 yy;
        yy.x = pack_bf16(acc[ct][0], acc[ct][1]);
        yy.y = pack_bf16(acc[ct][2], acc[ct][3]);
        *reinterpret_cast<u32x2*>(yrow + ct * 8 + qd * 2) = yy;
    }
}

// ---------------------------------------------------------------------------
// Count + rank: one membership per thread; atomic return value = rank.
// ---------------------------------------------------------------------------
__global__ __launch_bounds__(256) void count_kernel(
    const int* __restrict__ eu, const int* __restrict__ ei,
    int* __restrict__ offs, int* __restrict__ rank_u, int* __restrict__ rank_i)
{
    int t = blockIdx.x * 256 + threadIdx.x;
    if (t >= NMEMB) return;
    if (t < NEDGE) {
        int e = t;
        int key = eu[e] * 4 + e / E_N;
        rank_u[e] = atomicAdd(&offs[key], 1);
    } else {
        int e = t - NEDGE;
        int key = NKEYU + ei[e] * 4 + e / E_N;
        rank_i[e] = atomicAdd(&offs[key], 1);
    }
}

// ---------------------------------------------------------------------------
// Scan stage 1: per-chunk exclusive scan, chunk sums to bsum.
// ---------------------------------------------------------------------------
__global__ __launch_bounds__(256) void scan1_kernel(
    int* __restrict__ offs, int* __restrict__ bsum)
{
    __shared__ int s[256];
    int base = blockIdx.x * SCHUNK + threadIdx.x * 8;
    int v[8]; int tsum = 0;
    #pragma unroll
    for (int j = 0; j < 8; ++j) {
        int idx = base + j;
        v[j] = (idx < NKEYS) ? offs[idx] : 0;
        tsum += v[j];
    }
    s[threadIdx.x] = tsum; __syncthreads();
    for (int off = 1; off < 256; off <<= 1) {
        int t = (threadIdx.x >= off) ? s[threadIdx.x - off] : 0;
        __syncthreads(); s[threadIdx.x] += t; __syncthreads();
    }
    int excl = s[threadIdx.x] - tsum;
    if (threadIdx.x == 255) bsum[blockIdx.x] = s[255];
    int run = excl;
    #pragma unroll
    for (int j = 0; j < 8; ++j) {
        int idx = base + j;
        if (idx < NKEYS) offs[idx] = run;
        run += v[j];
    }
}

// ---------------------------------------------------------------------------
// Scan stage 2 (fused former scan2+scan3): each block locally prefix-sums
// bsum[0..bid) (293 L2-hot scalar reads, negligible) and adds to its chunk.
// Last block also writes offs[NKEYS] = total.
// ---------------------------------------------------------------------------
__global__ __launch_bounds__(256) void scan3_kernel(int* __restrict__ offs,
                                                    const int* __restrict__ bsum)
{
    __shared__ int s_add;
    if (threadIdx.x == 0) {
        int acc = 0;
        for (int j = 0; j < (int)blockIdx.x; ++j) acc += bsum[j];
        s_add = acc;
        if (blockIdx.x == SNBLK - 1)
            offs[NKEYS] = acc + bsum[SNBLK - 1];
    }
    __syncthreads();
    int add = s_add;
    int base = blockIdx.x * SCHUNK + threadIdx.x * 8;
    #pragma unroll
    for (int j = 0; j < 8; ++j) {
        int idx = base + j;
        if (idx < NKEYS) offs[idx] += add;
    }
}

// ---------------------------------------------------------------------------
// Atomic-free fill: pos = offs[key] + precomputed rank. Pair packed to 4 B:
// src (low 17 bits) | rounded float-top-15 weight bits (high 15).
// ---------------------------------------------------------------------------
__global__ __launch_bounds__(256) void fill_kernel(
    const int* __restrict__ eu, const int* __restrict__ ei,
    const float* __restrict__ ew,
    const int* __restrict__ offs,
    const int* __restrict__ rank_u, const int* __restrict__ rank_i,
    unsigned int* __restrict__ pairs)
{
    int t = blockIdx.x * 256 + threadIdx.x;
    if (t >= NMEMB) return;
    if (t < NEDGE) {
        int e = t;
        int b = e / E_N;
        int key = eu[e] * 4 + b;
        int pos = offs[key] + rank_u[e];
        unsigned int wb = __float_as_uint(ew[e]) + 0x10000u;  // round bit 17
        pairs[pos] = (wb & W_MASK) | (unsigned int)ei[e];
    } else {
        int e = t - NEDGE;
        int b = e / E_N;
        int key = NKEYU + ei[e] * 4 + b;
        int pos = offs[key] + rank_i[e];
        unsigned int wb = __float_as_uint(ew[e]) + 0x10000u;
        pairs[pos] = (wb & W_MASK) | (unsigned int)eu[e];
    }
}

// ---------------------------------------------------------------------------
// Gather (one side per dispatch): one wave per destination row; lane owns
// 2 dims (1 uint of 2 bf16). 4 behavior buckets in lockstep, x4-unrolled:
// 16 memberships / 16 independent T-row loads in flight per iteration
// (gather is L3-latency-bound: tA/tB fit L3; FETCH is L2-miss traffic).
// Dead slots clamp to previous valid index -> same pair/row, cache hits,
// zero extra HBM. Pair loads wave-uniform -> scalar path. NT stores.
// ---------------------------------------------------------------------------
__global__ __launch_bounds__(256) void gather_kernel(
    const unsigned int* __restrict__ T,
    const unsigned int* __restrict__ pairs, const int* __restrict__ offs,
    float* __restrict__ single, float* __restrict__ multi,
    int N, int keybase, const float* __restrict__ alpha_p)
{
    int r = blockIdx.x * 4 + (threadIdx.x >> 6);
    if (r >= N) return;
    int k0 = keybase + r * 4;

    float alpha = alpha_p[0];
    int lane = threadIdx.x & 63;

    int o0 = __builtin_amdgcn_readfirstlane(offs[k0]);
    int o1 = __builtin_amdgcn_readfirstlane(offs[k0 + 1]);
    int o2 = __builtin_amdgcn_readfirstlane(offs[k0 + 2]);
    int o3 = __builtin_amdgcn_readfirstlane(offs[k0 + 3]);
    int o4 = __builtin_amdgcn_readfirstlane(offs[k0 + 4]);
    int p0 = o0, p1 = o1, p2 = o2, p3 = o3;

    float ax0 = 0.f, ay0 = 0.f, ax1 = 0.f, ay1 = 0.f;
    float ax2 = 0.f, ay2 = 0.f, ax3 = 0.f, ay3 = 0.f;

    while ((p0 < o1) | (p1 < o2) | (p2 < o3) | (p3 < o4)) {
        #define SLOT(pp, oo, POS, prev, nm)                                  \
            int nm##v = (pp + POS) < oo;                                     \
            int nm##i = nm##v ? (pp + POS) : prev;
        // bucket 0
        SLOT(p0, o1, 0, o0, a0) SLOT(p0, o1, 1, a0i, b0)
        SLOT(p0, o1, 2, b0i, c0) SLOT(p0, o1, 3, c0i, d0)
        // bucket 1
        SLOT(p1, o2, 0, o0, a1) SLOT(p1, o2, 1, a1i, b1)
        SLOT(p1, o2, 2, b1i, c1) SLOT(p1, o2, 3, c1i, d1)
        // bucket 2
        SLOT(p2, o3, 0, o0, a2) SLOT(p2, o3, 1, a2i, b2)
        SLOT(p2, o3, 2, b2i, c2) SLOT(p2, o3, 3, c2i, d2)
        // bucket 3
        SLOT(p3, o4, 0, o0, a3) SLOT(p3, o4, 1, a3i, b3)
        SLOT(p3, o4, 2, b3i, c3) SLOT(p3, o4, 3, c3i, d3)
        #undef SLOT

        #define LOADS(nm)                                                    \
            unsigned int nm##s = __builtin_amdgcn_readfirstlane(pairs[nm##i]); \
            unsigned int nm##d = T[(size_t)(nm##s & SRC_MASK) * (D_N / 2) + lane]; \
            float nm##w = nm##v ? __uint_as_float(nm##s & W_MASK) : 0.f;
        LOADS(a0) LOADS(b0) LOADS(c0) LOADS(d0)
        LOADS(a1) LOADS(b1) LOADS(c1) LOADS(d1)
        LOADS(a2) LOADS(b2) LOADS(c2) LOADS(d2)
        LOADS(a3) LOADS(b3) LOADS(c3) LOADS(d3)
        #undef LOADS

        ax0 += a0w * __uint_as_float(a0d << 16)
             + b0w * __uint_as_float(b0d << 16)
             + c0w * __uint_as_float(c0d << 16)
             + d0w * __uint_as_float(d0d << 16);
        ay0 += a0w * __uint_as_float(a0d & 0xFFFF0000u)
             + b0w * __uint_as_float(b0d & 0xFFFF0000u)
             + c0w * __uint_as_float(c0d & 0xFFFF0000u)
             + d0w * __uint_as_float(d0d & 0xFFFF0000u);
        ax1 += a1w * __uint_as_float(a1d << 16)
             + b1w * __uint_as_float(b1d << 16)
             + c1w * __uint_as_float(c1d << 16)
             + d1w * __uint_as_float(d1d << 16);
        ay1 += a1w * __uint_as_float(a1d & 0xFFFF0000u)
             + b1w * __uint_as_float(b1d & 0xFFFF0000u)
             + c1w * __uint_as_float(c1d & 0xFFFF0000u)
             + d1w * __uint_as_float(d1d & 0xFFFF0000u);
        ax2 += a2w * __uint_as_float(a2d << 16)
             + b2w * __uint_as_float(b2d << 16)
             + c2w * __uint_as_float(c2d << 16)
             + d2w * __uint_as_float(d2d << 16);
        ay2 += a2w * __uint_as_float(a2d & 0xFFFF0000u)
             + b2w * __uint_as_float(b2d & 0xFFFF0000u)
             + c2w * __uint_as_float(c2d & 0xFFFF0000u)
             + d2w * __uint_as_float(d2d & 0xFFFF0000u);
        ax3 += a3w * __uint_as_float(a3d << 16)
             + b3w * __uint_as_float(b3d << 16)
             + c3w * __uint_as_float(c3d << 16)
             + d3w * __uint_as_float(d3d << 16);
        ay3 += a3w * __uint_as_float(a3d & 0xFFFF0000u)
             + b3w * __uint_as_float(b3d & 0xFFFF0000u)
             + c3w * __uint_as_float(c3d & 0xFFFF0000u)
             + d3w * __uint_as_float(d3d & 0xFFFF0000u);

        p0 += a0v + b0v + c0v + d0v;
        p1 += a1v + b1v + c1v + d1v;
        p2 += a2v + b2v + c2v + d2v;
        p3 += a3v + b3v + c3v + d3v;
    }

    float mx = 0.25f * (ax0 + ax1 + ax2 + ax3);
    float my = 0.25f * (ay0 + ay1 + ay2 + ay3);

    f32x2 o;
    o.x = ax0 >= 0.f ? ax0 : alpha * ax0;
    o.y = ay0 >= 0.f ? ay0 : alpha * ay0;
    __builtin_nontemporal_store(o, reinterpret_cast<f32x2*>(
        single + ((size_t)0 * N + r) * D_N + lane * 2));
    o.x = ax1 >= 0.f ? ax1 : alpha * ax1;
    o.y = ay1 >= 0.f ? ay1 : alpha * ay1;
    __builtin_nontemporal_store(o, reinterpret_cast<f32x2*>(
        single + ((size_t)1 * N + r) * D_N + lane * 2));
    o.x = ax2 >= 0.f ? ax2 : alpha * ax2;
    o.y = ay2 >= 0.f ? ay2 : alpha * ay2;
    __builtin_nontemporal_store(o, reinterpret_cast<f32x2*>(
        single + ((size_t)2 * N + r) * D_N + lane * 2));
    o.x = ax3 >= 0.f ? ax3 : alpha * ax3;
    o.y = ay3 >= 0.f ? ay3 : alpha * ay3;
    __builtin_nontemporal_store(o, reinterpret_cast<f32x2*>(
        single + ((size_t)3 * N + r) * D_N + lane * 2));

    o.x = mx >= 0.f ? mx : alpha * mx;
    o.y = my >= 0.f ? my : alpha * my;
    __builtin_nontemporal_store(o, reinterpret_cast<f32x2*>(
        multi + (size_t)r * D_N + lane * 2));
}

extern "C" void kernel_launch(void* const* d_in, const int* in_sizes, int n_in,
                              void* d_out, int out_size, void* d_ws, size_t ws_size,
                              hipStream_t stream) {
    const float* user_emb = (const float*)d_in[0];
    const float* item_emb = (const float*)d_in[1];
    const int*   eu       = (const int*)d_in[2];
    const int*   ei       = (const int*)d_in[3];
    const float* ew       = (const float*)d_in[4];
    const float* u_w      = (const float*)d_in[5];
    const float* i_w      = (const float*)d_in[6];
    const float* alpha    = (const float*)d_in[7];

    float* out      = (float*)d_out;
    float* multi_u  = out;                                      // [U][D]
    float* multi_i  = out + (size_t)U_N * D_N;                  // [I][D]
    float* single_u = out + (size_t)(U_N + I_N) * D_N;          // [B][U][D]
    float* single_i = single_u + (size_t)B_N * U_N * D_N;       // [B][I][D]

    // ranks live in multi_i's slot (consumed by fill; gather writes after).
    int* rank_u = (int*)multi_i;                                // 8 MB
    int* rank_i = rank_u + NEDGE;                               // 8 MB

    // d_ws: offs | bsum | pairs(4B packed) | tA(bf16) | tB(bf16) (~57 MB)
    int*  offs  = (int*)d_ws;                                   // NKEYS+4
    int*  bsum  = offs + (NKEYS + 4);                           // 512
    unsigned int* pairs =
        (unsigned int*)((char*)d_ws + ((((NKEYS + 4 + 512) * 4) + 255) & ~255));
    unsigned int* tA = pairs + NMEMB;                           // [I][64] 12.8 MB
    unsigned int* tB = tA + (size_t)I_N * (D_N / 2);            // [U][64] 25.6 MB

    transform_mfma_kernel<<<TB2I + TB2U + ZB, 256, 0, stream>>>(
        item_emb, user_emb, u_w, i_w, tA, tB, (int4*)offs);
    count_kernel<<<CB, 256, 0, stream>>>(eu, ei, offs, rank_u, rank_i);
    scan1_kernel<<<SNBLK, 256, 0, stream>>>(offs, bsum);
    scan3_kernel<<<SNBLK, 256, 0, stream>>>(offs, bsum);
    fill_kernel<<<CB, 256, 0, stream>>>(eu, ei, ew, offs,
                                        rank_u, rank_i, pairs);
    // split by side: per-dispatch working set = one bf16 pool only
    gather_kernel<<<(U_N + 3) / 4, 256, 0, stream>>>(
        tA, pairs, offs, single_u, multi_u, U_N, 0, alpha);
    gather_kernel<<<(I_N + 3) / 4, 256, 0, stream>>>(
        tB, pairs, offs, single_i, multi_i, I_N, NKEYU, alpha);
}

// Round 20
// 449.140 us; speedup vs baseline: 1.0294x; 1.0294x over previous
//
#include <hip/hip_runtime.h>

#define U_N 100000
#define I_N 50000
#define D_N 128
#define B_N 4
#define E_N 500000
#define NEDGE (B_N * E_N)            // 2,000,000
#define NKEYU (4 * U_N)              // keys u*4+b
#define NKEYS (NKEYU + 4 * I_N)      // 600,000
#define NMEMB (2 * NEDGE)            // 4,000,000
#define SCHUNK 2048
#define SNBLK ((NKEYS + SCHUNK - 1) / SCHUNK)   // 293
#define CB  ((NMEMB + 255) / 256)    // count/fill blocks
#define NZ4 ((NKEYS + 4) / 4)        // int4 count for offs zeroing
#define ZB  ((NZ4 + 255) / 256)      // zero-role blocks
#define TB2I ((I_N + 63) / 64)       // mfma-transform blocks, item side
#define TB2U ((U_N + 63) / 64)       // mfma-transform blocks, user side

#define SRC_MASK 0x1FFFFu            // low 17 bits: source row index
#define W_MASK   0xFFFE0000u         // high 15 bits: float top bits of weight

typedef float f32x2 __attribute__((ext_vector_type(2)));
typedef float f32x4 __attribute__((ext_vector_type(4)));
typedef short bf16x8 __attribute__((ext_vector_type(8)));
typedef unsigned int u32x4 __attribute__((ext_vector_type(4)));
typedef unsigned int u32x2 __attribute__((ext_vector_type(2)));

// round-to-nearest-even-ish bf16 pack of two floats -> uint (lo=a, hi=b)
__device__ inline unsigned int pack_bf16(float a, float b) {
    unsigned int ua = __float_as_uint(a);
    ua += 0x7FFFu + ((ua >> 16) & 1u);
    unsigned int ub = __float_as_uint(b);
    ub += 0x7FFFu + ((ub >> 16) & 1u);
    return (ua >> 16) | (ub & 0xFFFF0000u);
}

// ---------------------------------------------------------------------------
// MFMA transform: Y(bf16) = X @ W via mfma_f32_16x16x32_bf16, swapped
// operands (A = W^T frags from LDS, B = X rows). Zero-role blocks clear
// offs[]. (transform+count fusion rejected twice: r12/r14.)
// ---------------------------------------------------------------------------
__global__ __launch_bounds__(256) void transform_mfma_kernel(
    const float* __restrict__ item_emb, const float* __restrict__ user_emb,
    const float* __restrict__ u_w, const float* __restrict__ i_w,
    unsigned int* __restrict__ tA, unsigned int* __restrict__ tB,
    int4* __restrict__ offs4)
{
    __shared__ short wf[2048 * 8];   // 32 KB: A-frags, [kt(4)][ct(8)][lane(64)][8]

    const float* X; const float* W; unsigned int* Y; int N; int blk;
    if (blockIdx.x < TB2I) {
        X = item_emb; W = u_w; Y = tA; N = I_N; blk = blockIdx.x;
    } else if (blockIdx.x < TB2I + TB2U) {
        X = user_emb; W = i_w; Y = tB; N = U_N; blk = blockIdx.x - TB2I;
    } else {
        int t = (blockIdx.x - TB2I - TB2U) * 256 + threadIdx.x;
        if (t < NZ4) offs4[t] = make_int4(0, 0, 0, 0);
        return;
    }

    for (int f = threadIdx.x; f < 2048; f += 256) {
        int kt = f >> 9;
        int l  = f & 63;
        int c  = ((f >> 6) & 7) * 16 + (l & 15);
        int kb = kt * 32 + ((l >> 4) << 3);
        u32x4 q;
        q.x = pack_bf16(W[(kb + 0) * D_N + c], W[(kb + 1) * D_N + c]);
        q.y = pack_bf16(W[(kb + 2) * D_N + c], W[(kb + 3) * D_N + c]);
        q.z = pack_bf16(W[(kb + 4) * D_N + c], W[(kb + 5) * D_N + c]);
        q.w = pack_bf16(W[(kb + 6) * D_N + c], W[(kb + 7) * D_N + c]);
        *reinterpret_cast<u32x4*>(&wf[f * 8]) = q;
    }
    __syncthreads();

    int wave = threadIdx.x >> 6;
    int lane = threadIdx.x & 63;
    int rowbase = blk * 64 + wave * 16;
    if (rowbase >= N) return;

    f32x4 acc[8];
    #pragma unroll
    for (int ct = 0; ct < 8; ++ct) acc[ct] = (f32x4){0.f, 0.f, 0.f, 0.f};

    const float* xr0 = X + (size_t)(rowbase + (lane & 15)) * D_N
                         + ((lane >> 4) << 3);
    #pragma unroll
    for (int kt = 0; kt < 4; ++kt) {
        const float* xr = xr0 + kt * 32;
        float4 x0 = *reinterpret_cast<const float4*>(xr);
        float4 x1 = *reinterpret_cast<const float4*>(xr + 4);
        u32x4 bu;
        bu.x = pack_bf16(x0.x, x0.y);
        bu.y = pack_bf16(x0.z, x0.w);
        bu.z = pack_bf16(x1.x, x1.y);
        bu.w = pack_bf16(x1.z, x1.w);
        bf16x8 bfrag = __builtin_bit_cast(bf16x8, bu);
        #pragma unroll
        for (int ct = 0; ct < 8; ++ct) {
            bf16x8 afrag = *reinterpret_cast<const bf16x8*>(
                &wf[(((kt * 8 + ct) * 64) + lane) * 8]);
            acc[ct] = __builtin_amdgcn_mfma_f32_16x16x32_bf16(
                afrag, bfrag, acc[ct], 0, 0, 0);
        }
    }

    int row = rowbase + (lane & 15);
    int qd  = lane >> 4;
    unsigned int* yrow = Y + (size_t)row * (D_N / 2);
    #pragma unroll
    for (int ct = 0; ct < 8; ++ct) {
        u32x2 yy;
        yy.x = pack_bf16(acc[ct][0], acc[ct][1]);
        yy.y = pack_bf16(acc[ct][2], acc[ct][3]);
        *reinterpret_cast<u32x2*>(yrow + ct * 8 + qd * 2) = yy;
    }
}

// ---------------------------------------------------------------------------
// Count + rank: one membership per thread; atomic return value = rank.
// ---------------------------------------------------------------------------
__global__ __launch_bounds__(256) void count_kernel(
    const int* __restrict__ eu, const int* __restrict__ ei,
    int* __restrict__ offs, int* __restrict__ rank_u, int* __restrict__ rank_i)
{
    int t = blockIdx.x * 256 + threadIdx.x;
    if (t >= NMEMB) return;
    if (t < NEDGE) {
        int e = t;
        int key = eu[e] * 4 + e / E_N;
        rank_u[e] = atomicAdd(&offs[key], 1);
    } else {
        int e = t - NEDGE;
        int key = NKEYU + ei[e] * 4 + e / E_N;
        rank_i[e] = atomicAdd(&offs[key], 1);
    }
}

// ---------------------------------------------------------------------------
// Scan stage 1: per-chunk exclusive scan, chunk sums to bsum.
// ---------------------------------------------------------------------------
__global__ __launch_bounds__(256) void scan1_kernel(
    int* __restrict__ offs, int* __restrict__ bsum)
{
    __shared__ int s[256];
    int base = blockIdx.x * SCHUNK + threadIdx.x * 8;
    int v[8]; int tsum = 0;
    #pragma unroll
    for (int j = 0; j < 8; ++j) {
        int idx = base + j;
        v[j] = (idx < NKEYS) ? offs[idx] : 0;
        tsum += v[j];
    }
    s[threadIdx.x] = tsum; __syncthreads();
    for (int off = 1; off < 256; off <<= 1) {
        int t = (threadIdx.x >= off) ? s[threadIdx.x - off] : 0;
        __syncthreads(); s[threadIdx.x] += t; __syncthreads();
    }
    int excl = s[threadIdx.x] - tsum;
    if (threadIdx.x == 255) bsum[blockIdx.x] = s[255];
    int run = excl;
    #pragma unroll
    for (int j = 0; j < 8; ++j) {
        int idx = base + j;
        if (idx < NKEYS) offs[idx] = run;
        run += v[j];
    }
}

// ---------------------------------------------------------------------------
// Scan stage 2 (fused former scan2+scan3): each block locally prefix-sums
// bsum[0..bid) (293 L2-hot scalar reads, negligible) and adds to its chunk.
// Last block also writes offs[NKEYS] = total.
// ---------------------------------------------------------------------------
__global__ __launch_bounds__(256) void scan3_kernel(int* __restrict__ offs,
                                                    const int* __restrict__ bsum)
{
    __shared__ int s_add;
    if (threadIdx.x == 0) {
        int acc = 0;
        for (int j = 0; j < (int)blockIdx.x; ++j) acc += bsum[j];
        s_add = acc;
        if (blockIdx.x == SNBLK - 1)
            offs[NKEYS] = acc + bsum[SNBLK - 1];
    }
    __syncthreads();
    int add = s_add;
    int base = blockIdx.x * SCHUNK + threadIdx.x * 8;
    #pragma unroll
    for (int j = 0; j < 8; ++j) {
        int idx = base + j;
        if (idx < NKEYS) offs[idx] += add;
    }
}

// ---------------------------------------------------------------------------
// Atomic-free fill: pos = offs[key] + precomputed rank. Pair packed to 4 B:
// src (low 17 bits) | rounded float-top-15 weight bits (high 15).
// ---------------------------------------------------------------------------
__global__ __launch_bounds__(256) void fill_kernel(
    const int* __restrict__ eu, const int* __restrict__ ei,
    const float* __restrict__ ew,
    const int* __restrict__ offs,
    const int* __restrict__ rank_u, const int* __restrict__ rank_i,
    unsigned int* __restrict__ pairs)
{
    int t = blockIdx.x * 256 + threadIdx.x;
    if (t >= NMEMB) return;
    if (t < NEDGE) {
        int e = t;
        int b = e / E_N;
        int key = eu[e] * 4 + b;
        int pos = offs[key] + rank_u[e];
        unsigned int wb = __float_as_uint(ew[e]) + 0x10000u;  // round bit 17
        pairs[pos] = (wb & W_MASK) | (unsigned int)ei[e];
    } else {
        int e = t - NEDGE;
        int b = e / E_N;
        int key = NKEYU + ei[e] * 4 + b;
        int pos = offs[key] + rank_i[e];
        unsigned int wb = __float_as_uint(ew[e]) + 0x10000u;
        pairs[pos] = (wb & W_MASK) | (unsigned int)eu[e];
    }
}

// ---------------------------------------------------------------------------
// Gather (one side per dispatch): one wave per destination row; lane owns
// 2 dims (1 uint of 2 bf16). 4 behavior buckets in lockstep, x2-unrolled:
// 8 memberships in flight (x4 unroll regressed in r19: dead-slot issue
// overhead exceeds MLP gain at avg bucket len ~6.7). Pair loads
// wave-uniform -> scalar path. Dead slots clamp to previous valid index
// (cache hits, zero extra HBM). NT stores keep L2 for the row pool.
// ---------------------------------------------------------------------------
__global__ __launch_bounds__(256) void gather_kernel(
    const unsigned int* __restrict__ T,
    const unsigned int* __restrict__ pairs, const int* __restrict__ offs,
    float* __restrict__ single, float* __restrict__ multi,
    int N, int keybase, const float* __restrict__ alpha_p)
{
    int r = blockIdx.x * 4 + (threadIdx.x >> 6);
    if (r >= N) return;
    int k0 = keybase + r * 4;

    float alpha = alpha_p[0];
    int lane = threadIdx.x & 63;

    int o0 = __builtin_amdgcn_readfirstlane(offs[k0]);
    int o1 = __builtin_amdgcn_readfirstlane(offs[k0 + 1]);
    int o2 = __builtin_amdgcn_readfirstlane(offs[k0 + 2]);
    int o3 = __builtin_amdgcn_readfirstlane(offs[k0 + 3]);
    int o4 = __builtin_amdgcn_readfirstlane(offs[k0 + 4]);
    int p0 = o0, p1 = o1, p2 = o2, p3 = o3;

    float ax0 = 0.f, ay0 = 0.f, ax1 = 0.f, ay1 = 0.f;
    float ax2 = 0.f, ay2 = 0.f, ax3 = 0.f, ay3 = 0.f;

    while ((p0 < o1) | (p1 < o2) | (p2 < o3) | (p3 < o4)) {
        int a0 = p0 < o1, b0 = (p0 + 1) < o1;
        int a1 = p1 < o2, b1 = (p1 + 1) < o2;
        int a2 = p2 < o3, b2 = (p2 + 1) < o3;
        int a3 = p3 < o4, b3 = (p3 + 1) < o4;
        int i0a = a0 ? p0 : o0;         int i0b = b0 ? (p0 + 1) : i0a;
        int i1a = a1 ? p1 : o0;         int i1b = b1 ? (p1 + 1) : i1a;
        int i2a = a2 ? p2 : o0;         int i2b = b2 ? (p2 + 1) : i2a;
        int i3a = a3 ? p3 : o0;         int i3b = b3 ? (p3 + 1) : i3a;
        unsigned int s0a = __builtin_amdgcn_readfirstlane(pairs[i0a]);
        unsigned int s0b = __builtin_amdgcn_readfirstlane(pairs[i0b]);
        unsigned int s1a = __builtin_amdgcn_readfirstlane(pairs[i1a]);
        unsigned int s1b = __builtin_amdgcn_readfirstlane(pairs[i1b]);
        unsigned int s2a = __builtin_amdgcn_readfirstlane(pairs[i2a]);
        unsigned int s2b = __builtin_amdgcn_readfirstlane(pairs[i2b]);
        unsigned int s3a = __builtin_amdgcn_readfirstlane(pairs[i3a]);
        unsigned int s3b = __builtin_amdgcn_readfirstlane(pairs[i3b]);
        unsigned int d0a = T[(size_t)(s0a & SRC_MASK) * (D_N / 2) + lane];
        unsigned int d0b = T[(size_t)(s0b & SRC_MASK) * (D_N / 2) + lane];
        unsigned int d1a = T[(size_t)(s1a & SRC_MASK) * (D_N / 2) + lane];
        unsigned int d1b = T[(size_t)(s1b & SRC_MASK) * (D_N / 2) + lane];
        unsigned int d2a = T[(size_t)(s2a & SRC_MASK) * (D_N / 2) + lane];
        unsigned int d2b = T[(size_t)(s2b & SRC_MASK) * (D_N / 2) + lane];
        unsigned int d3a = T[(size_t)(s3a & SRC_MASK) * (D_N / 2) + lane];
        unsigned int d3b = T[(size_t)(s3b & SRC_MASK) * (D_N / 2) + lane];
        float w0a = a0 ? __uint_as_float(s0a & W_MASK) : 0.f;
        float w0b = b0 ? __uint_as_float(s0b & W_MASK) : 0.f;
        float w1a = a1 ? __uint_as_float(s1a & W_MASK) : 0.f;
        float w1b = b1 ? __uint_as_float(s1b & W_MASK) : 0.f;
        float w2a = a2 ? __uint_as_float(s2a & W_MASK) : 0.f;
        float w2b = b2 ? __uint_as_float(s2b & W_MASK) : 0.f;
        float w3a = a3 ? __uint_as_float(s3a & W_MASK) : 0.f;
        float w3b = b3 ? __uint_as_float(s3b & W_MASK) : 0.f;
        ax0 += w0a * __uint_as_float(d0a << 16)
             + w0b * __uint_as_float(d0b << 16);
        ay0 += w0a * __uint_as_float(d0a & 0xFFFF0000u)
             + w0b * __uint_as_float(d0b & 0xFFFF0000u);
        ax1 += w1a * __uint_as_float(d1a << 16)
             + w1b * __uint_as_float(d1b << 16);
        ay1 += w1a * __uint_as_float(d1a & 0xFFFF0000u)
             + w1b * __uint_as_float(d1b & 0xFFFF0000u);
        ax2 += w2a * __uint_as_float(d2a << 16)
             + w2b * __uint_as_float(d2b << 16);
        ay2 += w2a * __uint_as_float(d2a & 0xFFFF0000u)
             + w2b * __uint_as_float(d2b & 0xFFFF0000u);
        ax3 += w3a * __uint_as_float(d3a << 16)
             + w3b * __uint_as_float(d3b << 16);
        ay3 += w3a * __uint_as_float(d3a & 0xFFFF0000u)
             + w3b * __uint_as_float(d3b & 0xFFFF0000u);
        p0 += a0 + b0; p1 += a1 + b1; p2 += a2 + b2; p3 += a3 + b3;
    }

    float mx = 0.25f * (ax0 + ax1 + ax2 + ax3);
    float my = 0.25f * (ay0 + ay1 + ay2 + ay3);

    f32x2 o;
    o.x = ax0 >= 0.f ? ax0 : alpha * ax0;
    o.y = ay0 >= 0.f ? ay0 : alpha * ay0;
    __builtin_nontemporal_store(o, reinterpret_cast<f32x2*>(
        single + ((size_t)0 * N + r) * D_N + lane * 2));
    o.x = ax1 >= 0.f ? ax1 : alpha * ax1;
    o.y = ay1 >= 0.f ? ay1 : alpha * ay1;
    __builtin_nontemporal_store(o, reinterpret_cast<f32x2*>(
        single + ((size_t)1 * N + r) * D_N + lane * 2));
    o.x = ax2 >= 0.f ? ax2 : alpha * ax2;
    o.y = ay2 >= 0.f ? ay2 : alpha * ay2;
    __builtin_nontemporal_store(o, reinterpret_cast<f32x2*>(
        single + ((size_t)2 * N + r) * D_N + lane * 2));
    o.x = ax3 >= 0.f ? ax3 : alpha * ax3;
    o.y = ay3 >= 0.f ? ay3 : alpha * ay3;
    __builtin_nontemporal_store(o, reinterpret_cast<f32x2*>(
        single + ((size_t)3 * N + r) * D_N + lane * 2));

    o.x = mx >= 0.f ? mx : alpha * mx;
    o.y = my >= 0.f ? my : alpha * my;
    __builtin_nontemporal_store(o, reinterpret_cast<f32x2*>(
        multi + (size_t)r * D_N + lane * 2));
}

extern "C" void kernel_launch(void* const* d_in, const int* in_sizes, int n_in,
                              void* d_out, int out_size, void* d_ws, size_t ws_size,
                              hipStream_t stream) {
    const float* user_emb = (const float*)d_in[0];
    const float* item_emb = (const float*)d_in[1];
    const int*   eu       = (const int*)d_in[2];
    const int*   ei       = (const int*)d_in[3];
    const float* ew       = (const float*)d_in[4];
    const float* u_w      = (const float*)d_in[5];
    const float* i_w      = (const float*)d_in[6];
    const float* alpha    = (const float*)d_in[7];

    float* out      = (float*)d_out;
    float* multi_u  = out;                                      // [U][D]
    float* multi_i  = out + (size_t)U_N * D_N;                  // [I][D]
    float* single_u = out + (size_t)(U_N + I_N) * D_N;          // [B][U][D]
    float* single_i = single_u + (size_t)B_N * U_N * D_N;       // [B][I][D]

    // ranks live in multi_i's slot (consumed by fill; gather writes after).
    int* rank_u = (int*)multi_i;                                // 8 MB
    int* rank_i = rank_u + NEDGE;                               // 8 MB

    // d_ws: offs | bsum | pairs(4B packed) | tA(bf16) | tB(bf16) (~57 MB)
    int*  offs  = (int*)d_ws;                                   // NKEYS+4
    int*  bsum  = offs + (NKEYS + 4);                           // 512
    unsigned int* pairs =
        (unsigned int*)((char*)d_ws + ((((NKEYS + 4 + 512) * 4) + 255) & ~255));
    unsigned int* tA = pairs + NMEMB;                           // [I][64] 12.8 MB
    unsigned int* tB = tA + (size_t)I_N * (D_N / 2);            // [U][64] 25.6 MB

    transform_mfma_kernel<<<TB2I + TB2U + ZB, 256, 0, stream>>>(
        item_emb, user_emb, u_w, i_w, tA, tB, (int4*)offs);
    count_kernel<<<CB, 256, 0, stream>>>(eu, ei, offs, rank_u, rank_i);
    scan1_kernel<<<SNBLK, 256, 0, stream>>>(offs, bsum);
    scan3_kernel<<<SNBLK, 256, 0, stream>>>(offs, bsum);
    fill_kernel<<<CB, 256, 0, stream>>>(eu, ei, ew, offs,
                                        rank_u, rank_i, pairs);
    // split by side: per-dispatch working set = one bf16 pool only
    gather_kernel<<<(U_N + 3) / 4, 256, 0, stream>>>(
        tA, pairs, offs, single_u, multi_u, U_N, 0, alpha);
    gather_kernel<<<(I_N + 3) / 4, 256, 0, stream>>>(
        tB, pairs, offs, single_i, multi_i, I_N, NKEYU, alpha);
}